// Round 7
// baseline (422.609 us; speedup 1.0000x reference)
//
#include <hip/hip_runtime.h>
#include <hip/hip_fp16.h>

// GCN layer: relu(A1·(xW1) + A2·(xW2) + b), B=4, N=50000, F=64, E=800000.
// fp32 in/out, int32 indices. pre stored fp16 (gather operand; fp32 accum).
// CSR concatenated over 2N rows (support1 then support2).
// CSR build is octant-binned: edges grouped by srow/6250 (16 buckets) so the
// rank-atomics and the cv scatter each touch a small, L2-resident window;
// the scatter grid is laid out blockIdx%8==octant to pin octants to XCDs
// (round-robin heuristic; correctness does not depend on it).
#define NB 4
#define NN 50000
#define FF 64
#define NN2 (2 * NN)
#define OCT 6250                      // rows per octant (8*6250 = 50000)
#define NBKT 16                       // 2 supports x 8 octants
#define SCAN_BLOCKS ((NN2 + 255) / 256)   // 391
#define BIN_U 8
#define BIN_T 256
#define BIN_CHUNK (BIN_U * BIN_T)     // 2048 edges per block

// ---------------- fused GEMM: pre{1,2}[n][f] = half4{ x[b][n][:]·W{1,2}[:,f] }
__global__ void gemm_xw2(const float* __restrict__ x,
                         const float* __restrict__ W1, const float* __restrict__ W2,
                         uint2* __restrict__ pre1, uint2* __restrict__ pre2) {
    __shared__ float Ws1[FF][FF];      // 16 KB
    __shared__ float Ws2[FF][FF];      // 16 KB
    __shared__ float xs[NB][4][FF];    // 4 KB
    const int tid = threadIdx.x;
#pragma unroll
    for (int i = 0; i < 16; ++i) {
        int idx = tid + i * 256;
        Ws1[idx >> 6][idx & 63] = W1[idx];
        Ws2[idx >> 6][idx & 63] = W2[idx];
    }
    const int r = tid >> 6, f = tid & 63;
    const int base = blockIdx.x * 16;
#pragma unroll
    for (int g = 0; g < 4; ++g) {
        const int row = base + g * 4 + r;
        __syncthreads();
#pragma unroll
        for (int b = 0; b < NB; ++b)
            xs[b][r][f] = x[((size_t)b * NN + row) * FF + f];   // coalesced
        __syncthreads();
        float p0 = 0.f, p1 = 0.f, p2 = 0.f, p3 = 0.f;
        float q0 = 0.f, q1 = 0.f, q2 = 0.f, q3 = 0.f;
#pragma unroll
        for (int k = 0; k < FF; ++k) {
            const float w1 = Ws1[k][f], w2 = Ws2[k][f];
            const float x0 = xs[0][r][k], x1 = xs[1][r][k];
            const float x2 = xs[2][r][k], x3 = xs[3][r][k];
            p0 += x0 * w1; p1 += x1 * w1; p2 += x2 * w1; p3 += x3 * w1;
            q0 += x0 * w2; q1 += x1 * w2; q2 += x2 * w2; q3 += x3 * w2;
        }
        const size_t o = (size_t)row * FF + f;
        __half2 h01 = __floats2half2_rn(p0, p1), h23 = __floats2half2_rn(p2, p3);
        pre1[o] = make_uint2(*(unsigned*)&h01, *(unsigned*)&h23);
        h01 = __floats2half2_rn(q0, q1); h23 = __floats2half2_rn(q2, q3);
        pre2[o] = make_uint2(*(unsigned*)&h01, *(unsigned*)&h23);
    }
}

// ---------------- octant binning -------------------------------------------
// Pass A: exact bucket sizes (LDS histogram, 16 global atomics per block).
__global__ void bucket_count(const int* __restrict__ r1, const int* __restrict__ r2,
                             int* __restrict__ bcnt, int E) {
    __shared__ int lcnt[NBKT];
    const int tid = threadIdx.x;
    if (tid < NBKT) lcnt[tid] = 0;
    __syncthreads();
    const int base = blockIdx.x * BIN_CHUNK;
#pragma unroll
    for (int u = 0; u < BIN_U; ++u) {
        const int e = base + u * BIN_T + tid;
        if (e < E)          atomicAdd(&lcnt[r1[e] / OCT], 1);
        else if (e < 2 * E) atomicAdd(&lcnt[8 + r2[e - E] / OCT], 1);
    }
    __syncthreads();
    if (tid < NBKT && lcnt[tid]) atomicAdd(&bcnt[tid], lcnt[tid]);
}

// Tiny serial scan of 16 bucket counts -> bbase[17]; init bucket cursors.
__global__ void scan_buckets(const int* __restrict__ bcnt,
                             int* __restrict__ bbase, int* __restrict__ bcur) {
    if (threadIdx.x == 0) {
        int acc = 0;
        for (int b = 0; b < NBKT; ++b) { bbase[b] = acc; bcur[b] = acc; acc += bcnt[b]; }
        bbase[NBKT] = acc;
    }
}

// Pass B: bin edges into bucket-major arrays (block-local counting sort; per
// bucket each block writes one contiguous range -> L2-friendly).
__global__ void bin_edges(const int* __restrict__ r1, const int* __restrict__ c1,
                          const float* __restrict__ v1,
                          const int* __restrict__ r2, const int* __restrict__ c2,
                          const float* __restrict__ v2,
                          int* __restrict__ bcur, int* __restrict__ brow,
                          int2* __restrict__ bcv, int E) {
    __shared__ int lcnt[NBKT], lbase[NBKT];
    const int tid = threadIdx.x;
    if (tid < NBKT) lcnt[tid] = 0;
    __syncthreads();
    const int base = blockIdx.x * BIN_CHUNK;
    int  bk[BIN_U], rk[BIN_U], sr[BIN_U], co[BIN_U], va[BIN_U];
#pragma unroll
    for (int u = 0; u < BIN_U; ++u) {
        const int e = base + u * BIN_T + tid;
        int srow = -1, col = 0, val = 0;
        if (e < E)          { srow = r1[e];          col = c1[e];     val = __float_as_int(v1[e]); }
        else if (e < 2 * E) { srow = NN + r2[e - E]; col = c2[e - E]; val = __float_as_int(v2[e - E]); }
        if (srow >= 0) {
            const int b = srow / OCT;
            bk[u] = b; sr[u] = srow; co[u] = col; va[u] = val;
            rk[u] = atomicAdd(&lcnt[b], 1);
        } else bk[u] = -1;
    }
    __syncthreads();
    if (tid < NBKT) lbase[tid] = lcnt[tid] ? atomicAdd(&bcur[tid], lcnt[tid]) : 0;
    __syncthreads();
#pragma unroll
    for (int u = 0; u < BIN_U; ++u) {
        if (bk[u] >= 0) {
            const int pos = lbase[bk[u]] + rk[u];
            brow[pos] = sr[u];
            bcv[pos]  = make_int2(co[u], va[u]);
        }
    }
}

// Rank within row (counts atomics now confined to ~25 KB hot window/bucket).
__global__ void hist_rank_binned(const int* __restrict__ brow, int* __restrict__ counts,
                                 int* __restrict__ rank, int n) {
    const int i = blockIdx.x * blockDim.x + threadIdx.x;
    if (i < n) rank[i] = atomicAdd(&counts[brow[i]], 1);
}

// ---------------- hierarchical scan over 2N row counts ----------------------
__global__ void scan_partial(const int* __restrict__ counts,
                             int* __restrict__ rowptr, int* __restrict__ blocksum) {
    __shared__ int buf[256];
    const int tid = threadIdx.x;
    const int i = blockIdx.x * 256 + tid;
    const int v = (i < NN2) ? counts[i] : 0;
    buf[tid] = v;
    __syncthreads();
#pragma unroll
    for (int off = 1; off < 256; off <<= 1) {
        int t = (tid >= off) ? buf[tid - off] : 0;
        __syncthreads();
        buf[tid] += t;
        __syncthreads();
    }
    if (i < NN2) rowptr[i] = buf[tid] - v;
    if (tid == 255) blocksum[blockIdx.x] = buf[255];
}

__global__ void scan_sums(int* __restrict__ blocksum, int* __restrict__ rowptr) {
    __shared__ int buf[512];
    const int tid = threadIdx.x;
    const int v = (tid < SCAN_BLOCKS) ? blocksum[tid] : 0;
    buf[tid] = v;
    __syncthreads();
#pragma unroll
    for (int off = 1; off < 512; off <<= 1) {
        int t = (tid >= off) ? buf[tid - off] : 0;
        __syncthreads();
        buf[tid] += t;
        __syncthreads();
    }
    if (tid < SCAN_BLOCKS) blocksum[tid] = buf[tid] - v;
    if (tid == 511) rowptr[NN2] = buf[511];
}

__global__ void scan_add(int* __restrict__ rowptr, const int* __restrict__ blocksum) {
    const int i = blockIdx.x * 256 + threadIdx.x;
    if (i < NN2) rowptr[i] += blocksum[blockIdx.x];
}

// ---------------- scatter, octant-pinned ------------------------------------
// blockIdx%8 = octant -> (heuristically) all writers of one octant's cv window
// (~1.6 MB) share an XCD L2; lines fill before writeback.
__global__ void scatter_binned(const int* __restrict__ brow, const int2* __restrict__ bcv,
                               const int* __restrict__ rank, const int* __restrict__ rowptr,
                               const int* __restrict__ bbase, int2* __restrict__ cv) {
    const int o = blockIdx.x & 7;
    const int k = blockIdx.x >> 3;
    const int K = gridDim.x >> 3;
#pragma unroll
    for (int s = 0; s < 2; ++s) {
        const int beg = bbase[s * 8 + o], end = bbase[s * 8 + o + 1];
        for (int i = beg + k * 256 + threadIdx.x; i < end; i += K * 256)
            cv[rowptr[brow[i]] + rank[i]] = bcv[i];
    }
}

// ---------------- fused SpMM: out = relu(A1·pre1 + A2·pre2 + b) -------------
__device__ __forceinline__ void acc_seg(int beg, int end,
                                        const int2* __restrict__ cv,
                                        const uint2* __restrict__ pre, int f,
                                        float& a0, float& a1, float& a2, float& a3) {
    int j = beg;
    for (; j + 8 <= end; j += 8) {                 // 8 gathers in flight
        int2 e[8]; uint2 g[8];
#pragma unroll
        for (int u = 0; u < 8; ++u) e[u] = cv[j + u];
#pragma unroll
        for (int u = 0; u < 8; ++u) g[u] = pre[(size_t)e[u].x * FF + f];
#pragma unroll
        for (int u = 0; u < 8; ++u) {
            const float v = __int_as_float(e[u].y);
            const float2 lo = __half22float2(*(const __half2*)&g[u].x);
            const float2 hi = __half22float2(*(const __half2*)&g[u].y);
            a0 += v * lo.x; a1 += v * lo.y; a2 += v * hi.x; a3 += v * hi.y;
        }
    }
    for (; j < end; ++j) {
        const int2 e = cv[j];
        const uint2 g = pre[(size_t)e.x * FF + f];
        const float v = __int_as_float(e.y);
        const float2 lo = __half22float2(*(const __half2*)&g.x);
        const float2 hi = __half22float2(*(const __half2*)&g.y);
        a0 += v * lo.x; a1 += v * lo.y; a2 += v * hi.x; a3 += v * hi.y;
    }
}

__global__ void spmm_fused(const int* __restrict__ rowptr, const int2* __restrict__ cv,
                           const uint2* __restrict__ pre1, const uint2* __restrict__ pre2,
                           const float* __restrict__ bias, float* __restrict__ out) {
    const int tid = blockIdx.x * blockDim.x + threadIdx.x;
    const int r = tid >> 6;
    if (r >= NN) return;
    const int f = tid & 63;
    float a0 = 0.f, a1 = 0.f, a2 = 0.f, a3 = 0.f;
    acc_seg(rowptr[r],      rowptr[r + 1],      cv, pre1, f, a0, a1, a2, a3);
    acc_seg(rowptr[NN + r], rowptr[NN + r + 1], cv, pre2, f, a0, a1, a2, a3);
    const float bf = bias[f];
    a0 += bf; a1 += bf; a2 += bf; a3 += bf;
    const size_t o = (size_t)r * FF + f;
    const size_t s = (size_t)NN * FF;
    out[o]         = a0 > 0.f ? a0 : 0.f;
    out[o + s]     = a1 > 0.f ? a1 : 0.f;
    out[o + 2 * s] = a2 > 0.f ? a2 : 0.f;
    out[o + 3 * s] = a3 > 0.f ? a3 : 0.f;
}

extern "C" void kernel_launch(void* const* d_in, const int* in_sizes, int n_in,
                              void* d_out, int out_size, void* d_ws, size_t ws_size,
                              hipStream_t stream) {
    const float* x     = (const float*)d_in[0];
    const int*   rows1 = (const int*)d_in[1];
    const int*   cols1 = (const int*)d_in[2];
    const float* vals1 = (const float*)d_in[3];
    const int*   rows2 = (const int*)d_in[4];
    const int*   cols2 = (const int*)d_in[5];
    const float* vals2 = (const float*)d_in[6];
    const float* W1    = (const float*)d_in[7];
    const float* W2    = (const float*)d_in[8];
    const float* bias  = (const float*)d_in[9];
    float* out = (float*)d_out;

    const int E = in_sizes[1];

    // Workspace (~65 MB). Region P (51.2 MB) is time-shared:
    //   build phase : brow[2E] | bcv[2E] | rank[2E]   (25.6 MB, dead after scatter)
    //   gemm/spmm   : pre1 | pre2                      (51.2 MB, born at gemm)
    char* w = (char*)d_ws;
    auto align = [](size_t v) { return (v + 255) & ~(size_t)255; };
    char* P = w;                                  w += align((size_t)2 * NN * FF * 8);
    int2*  cv       = (int2*)w;                   w += align((size_t)2 * E * 8);
    int*   counts   = (int*)w;                    w += align(((size_t)NN2 + 2 * NBKT) * 4);
    int*   rowptr   = (int*)w;                    w += align(((size_t)NN2 + 1) * 4);
    int*   blocksum = (int*)w;                    w += align((size_t)SCAN_BLOCKS * 4);
    int*   bbase    = (int*)w;                    w += align((size_t)(NBKT + 1) * 4);
    int*   bcnt = counts + NN2;                   // zeroed together with counts
    int*   bcur = counts + NN2 + NBKT;

    char* p = P;
    int*  brow = (int*)p;                         p += align((size_t)2 * E * 4);
    int2* bcv  = (int2*)p;                        p += align((size_t)2 * E * 8);
    int*  rank = (int*)p;
    uint2* pre1 = (uint2*)P;
    uint2* pre2 = (uint2*)(P + (size_t)NN * FF * 8);

    const int gemm_blocks  = NN / 16;                     // 3125
    const int bin_blocks   = (2 * E + BIN_CHUNK - 1) / BIN_CHUNK;   // 782
    const int edge2_blocks = (2 * E + 255) / 256;         // 6250
    const int spmm_blocks  = (NN * FF + 255) / 256;       // 12500

    hipMemsetAsync(counts, 0, ((size_t)NN2 + 2 * NBKT) * 4, stream);
    bucket_count<<<bin_blocks, BIN_T, 0, stream>>>(rows1, rows2, bcnt, E);
    scan_buckets<<<1, 64, 0, stream>>>(bcnt, bbase, bcur);
    bin_edges<<<bin_blocks, BIN_T, 0, stream>>>(rows1, cols1, vals1,
                                                rows2, cols2, vals2,
                                                bcur, brow, bcv, E);
    hist_rank_binned<<<edge2_blocks, 256, 0, stream>>>(brow, counts, rank, 2 * E);
    scan_partial<<<SCAN_BLOCKS, 256, 0, stream>>>(counts, rowptr, blocksum);
    scan_sums<<<1, 512, 0, stream>>>(blocksum, rowptr);
    scan_add<<<SCAN_BLOCKS, 256, 0, stream>>>(rowptr, blocksum);
    scatter_binned<<<8 * 392, 256, 0, stream>>>(brow, bcv, rank, rowptr, bbase, cv);
    gemm_xw2<<<gemm_blocks, 256, 0, stream>>>(x, W1, W2, pre1, pre2);
    spmm_fused<<<spmm_blocks, 256, 0, stream>>>(rowptr, cv, pre1, pre2, bias, out);
}